// Round 9
// baseline (325.895 us; speedup 1.0000x reference)
//
#include <hip/hip_runtime.h>
#include <stdint.h>

#define N_ROWS 32768
#define D_DIM  1024
#define C_TREES 64
#define K_LEAF 16
#define M_OUT  1024

typedef _Float16 half8v __attribute__((ext_vector_type(8)));
typedef _Float16 half4v __attribute__((ext_vector_type(4)));

// 8 x (f32 += f16) in 8 VOP3P ops: v_fma_mix_f32 acc, h, 1.0, acc
__device__ __forceinline__ void fma8(float* a, float4 v) {
    asm("v_fma_mix_f32 %0, %8, 1.0, %0 op_sel_hi:[1,0,0]\n\t"
        "v_fma_mix_f32 %1, %8, 1.0, %1 op_sel:[1,0,0] op_sel_hi:[1,0,0]\n\t"
        "v_fma_mix_f32 %2, %9, 1.0, %2 op_sel_hi:[1,0,0]\n\t"
        "v_fma_mix_f32 %3, %9, 1.0, %3 op_sel:[1,0,0] op_sel_hi:[1,0,0]\n\t"
        "v_fma_mix_f32 %4, %10, 1.0, %4 op_sel_hi:[1,0,0]\n\t"
        "v_fma_mix_f32 %5, %10, 1.0, %5 op_sel:[1,0,0] op_sel_hi:[1,0,0]\n\t"
        "v_fma_mix_f32 %6, %11, 1.0, %6 op_sel_hi:[1,0,0]\n\t"
        "v_fma_mix_f32 %7, %11, 1.0, %7 op_sel:[1,0,0] op_sel_hi:[1,0,0]"
        : "+v"(a[0]), "+v"(a[1]), "+v"(a[2]), "+v"(a[3]),
          "+v"(a[4]), "+v"(a[5]), "+v"(a[6]), "+v"(a[7])
        : "v"(v.x), "v"(v.y), "v"(v.z), "v"(v.w));
}

// ---------------- Kernel A: transpose lut (M, C*K=1024) -> lutT (C*K, M) ----------------
__global__ __launch_bounds__(256) void k_transpose(const float* __restrict__ lut,
                                                   float* __restrict__ lutT) {
    __shared__ float tile[32][33];
    int bx = blockIdx.x;
    int by = blockIdx.y;
    int tx = threadIdx.x;
    int ty = threadIdx.y;
    int src_col = bx * 32 + tx;
#pragma unroll
    for (int i = 0; i < 4; ++i) {
        int src_row = by * 32 + ty + i * 8;
        tile[ty + i * 8][tx] = lut[(size_t)src_row * 1024 + src_col];
    }
    __syncthreads();
    int dst_col = by * 32 + tx;
#pragma unroll
    for (int i = 0; i < 4; ++i) {
        int dst_row = bx * 32 + ty + i * 8;
        lutT[(size_t)dst_row * 1024 + dst_col] = tile[tx][ty + i * 8];
    }
}

// ---------------- Kernel A2t: build pair tables, f16, m-tile-contiguous ----------------
// Pt[tile][p*256+j][32 m] (halves): tile = m/32. Slice (tile,p) = contiguous 16KB.
__global__ __launch_bounds__(256) void k_build_ht(const float* __restrict__ lutT,
                                                  _Float16* __restrict__ Pt) {
    int j = blockIdx.x;           // 0..255 code
    int p = blockIdx.y;           // 0..31 pair
    int klo = j & 15;
    int khi = j >> 4;
    int t = threadIdx.x;          // 0..255, 4 m each
    const float4* a = (const float4*)lutT + (size_t)(p * 32 + klo) * 256;
    const float4* b = (const float4*)lutT + (size_t)(p * 32 + 16 + khi) * 256;
    float4 va = a[t];
    float4 vb = b[t];
    half4v hv;
    hv.x = (_Float16)(va.x + vb.x);
    hv.y = (_Float16)(va.y + vb.y);
    hv.z = (_Float16)(va.z + vb.z);
    hv.w = (_Float16)(va.w + vb.w);
    int tile = t >> 3;            // m-tile (m = 4t)
    ((half4v*)Pt)[(size_t)tile * 65536 + (size_t)(p * 256 + j) * 8 + (t & 7)] = hv;
}

// ---------------- Kernel B3: encode pair codes, pre-scaled u16 ----------------
// code16[p][n] = ((leafB<<4)|leafA) << 2   (row offset in float4 units of a slice)
__global__ __launch_bounds__(256) void k_encode3(const float* __restrict__ in,
                                                 const int* __restrict__ dims,
                                                 const float* __restrict__ th,
                                                 uint16_t* __restrict__ code16) {
    __shared__ float rows[8][1028];   // +4 pad
    __shared__ float th_s[960];
    __shared__ int   dims_s[256];
    int t = threadIdx.x;
    dims_s[t] = dims[t];
    for (int i = t; i < 960; i += 256) th_s[i] = th[i];
    int n0 = blockIdx.x * 8;
    const float4* in4 = (const float4*)(in + (size_t)n0 * 1024);
#pragma unroll
    for (int i = 0; i < 8; ++i) {
        ((float4*)&rows[i][0])[t] = in4[i * 256 + t];
    }
    __syncthreads();
    int p = t >> 3;
    int r = t & 7;
    const float* trow = &rows[r][0];
    int cA = 2 * p, cB = 2 * p + 1;

    float xA[4], xB[4];
#pragma unroll
    for (int l = 0; l < 4; ++l) {
        xA[l] = trow[dims_s[cA * 4 + l]];
        xB[l] = trow[dims_s[cB * 4 + l]];
    }
    const float* tAp = &th_s[cA * 15];
    const float* tBp = &th_s[cB * 15];
    unsigned mA = 0, mB = 0;
#pragma unroll
    for (int i = 0; i < 15; ++i) {
        const int d = (i == 0) ? 0 : (i < 3) ? 1 : (i < 7) ? 2 : 3;
        mA |= ((unsigned)(xA[d] > tAp[i])) << i;
        mB |= ((unsigned)(xB[d] > tBp[i])) << i;
    }
    int nA = 0, nB = 0;
#pragma unroll
    for (int l = 0; l < 4; ++l) {
        nA = 2 * nA + 1 + ((mA >> nA) & 1);
        nB = 2 * nB + 1 + ((mB >> nB) & 1);
    }
    code16[(size_t)p * N_ROWS + n0 + r] =
        (uint16_t)(((nB - 15) << 6) | ((nA - 15) << 2));
}

// ---------------- Kernel C7: split-pipe accumulate, cheap addressing + f16 pairing ----
// out[n,m] = sum_p Pt[tile][p*256+code(p,n)][m...]. 16 iters: p=2i via LDS ring,
// p=2i+1 via direct L1/L2 gather. Pair (even+odd) with v_pk_add_f16, then 8 fma_mix.
// Codes pre-scaled: index = c | mc (disjoint bits) -> 2-3 VALU per access.
__global__ __launch_bounds__(512, 6) void k_accum7(const _Float16* __restrict__ Pt,
                                                   const uint16_t* __restrict__ code16,
                                                   float* __restrict__ out) {
    __shared__ float4 sl[3][1024];    // 3 x 16KB ring

    int t  = threadIdx.x;
    int mc = t & 3;                   // float4 chunk within 64B row
    int ng = t >> 2;                  // 0..127, each owns 4 n rows
    int tile = blockIdx.x;            // m0 = tile*32
    int n0 = blockIdx.y * 512;
    const float4* Pt4 = (const float4*)Pt + (size_t)tile * 32768;  // tile base
    const float4* slf = &sl[0][0];

    auto stage = [&](int buf, int slice) {
#pragma unroll
        for (int it = 0; it < 2; ++it) {
            int idx = t + it * 512;
            const float4* src = Pt4 + slice * 1024 + idx;   // contiguous 16KB
            __builtin_amdgcn_global_load_lds((const __attribute__((address_space(1))) void*)src,
                                             (__attribute__((address_space(3))) void*)(&sl[buf][idx]),
                                             16, 0, 0);
        }
    };

    float acc[4][8];
#pragma unroll
    for (int j = 0; j < 4; ++j)
#pragma unroll
        for (int q = 0; q < 8; ++q) acc[j][q] = 0.f;

    const uint16_t* cp16 = code16 + n0 + ng * 4;
    uint64_t cdE = *(const uint64_t*)cp16;                     // p=0 (4 n, u16 each)
    uint64_t cdO = *(const uint64_t*)(cp16 + N_ROWS);          // p=1
    asm volatile("" ::: "memory");
    stage(0, 0);                      // slice p=0
    stage(1, 2);                      // slice p=2
    __syncthreads();                  // full drain once: slices 0,2 resident
    int bc = 0;

    for (int i = 0; i < 16; ++i) {
        // Odd-slice gathers: o = 2i+1 (uniform base -> saddr; voffset = c | mc)
        const float4* Po = Pt4 + (size_t)(2 * i + 1) * 1024;
        uint32_t oLo = (uint32_t)cdO, oHi = (uint32_t)(cdO >> 32);
        float4 g0 = Po[(oLo & 0xffffu) | mc];
        float4 g1 = Po[(oLo >> 16)     | mc];
        float4 g2 = Po[(oHi & 0xffffu) | mc];
        float4 g3 = Po[(oHi >> 16)     | mc];

        // Next iteration's codes.
        int ip = (i < 15) ? (i + 1) : 0;
        uint64_t cdE2 = *(const uint64_t*)(cp16 + (size_t)(2 * ip) * N_ROWS);
        uint64_t cdO2 = *(const uint64_t*)(cp16 + (size_t)(2 * ip + 1) * N_ROWS);
        asm volatile("" ::: "memory");   // pin: gathers+codes issue before stage

        // Stage even slice for iter i+2 (dummy re-stage at tail).
        int ns = (i < 14) ? (2 * i + 4) : 0;
        int bs = bc + 2; if (bs >= 3) bs -= 3;
        stage(bs, ns);

        // Even slice from LDS, pair with gathered odd values in f16, accumulate.
        uint32_t eLo = (uint32_t)cdE, eHi = (uint32_t)(cdE >> 32);
        int sbase = bc << 10;
        float4 l0 = slf[sbase + ((eLo & 0xffffu) | mc)];
        float4 l1 = slf[sbase + ((eLo >> 16)     | mc)];
        float4 l2 = slf[sbase + ((eHi & 0xffffu) | mc)];
        float4 l3 = slf[sbase + ((eHi >> 16)     | mc)];

        half8v s0 = __builtin_bit_cast(half8v, l0) + __builtin_bit_cast(half8v, g0);
        half8v s1 = __builtin_bit_cast(half8v, l1) + __builtin_bit_cast(half8v, g1);
        half8v s2 = __builtin_bit_cast(half8v, l2) + __builtin_bit_cast(half8v, g2);
        half8v s3 = __builtin_bit_cast(half8v, l3) + __builtin_bit_cast(half8v, g3);
        fma8(acc[0], __builtin_bit_cast(float4, s0));
        fma8(acc[1], __builtin_bit_cast(float4, s1));
        fma8(acc[2], __builtin_bit_cast(float4, s2));
        fma8(acc[3], __builtin_bit_cast(float4, s3));

        // Keep newer stages/codes in flight across the barrier; older all drained
        // by the compiler's gather-waits above.
        asm volatile("s_waitcnt vmcnt(4)" ::: "memory");
        asm volatile("s_barrier" ::: "memory");

        cdE = cdE2; cdO = cdO2;
        bc = (bc == 2) ? 0 : bc + 1;
    }

    float4* out4 = (float4*)out;
#pragma unroll
    for (int j = 0; j < 4; ++j) {
        int n = n0 + ng * 4 + j;
        size_t base = (size_t)n * 256 + tile * 8 + mc * 2;
        out4[base]     = make_float4(acc[j][0], acc[j][1], acc[j][2], acc[j][3]);
        out4[base + 1] = make_float4(acc[j][4], acc[j][5], acc[j][6], acc[j][7]);
    }
}

// ================= Fallback path (ws too small): round-1 kernels =================
__global__ __launch_bounds__(256) void k_encode(const float* __restrict__ in,
                                                const int* __restrict__ dims,
                                                const float* __restrict__ th,
                                                uint8_t* __restrict__ leaf) {
    __shared__ float rows[8][1028];
    __shared__ float th_s[960];
    __shared__ int   dims_s[256];
    int t = threadIdx.x;
    dims_s[t] = dims[t];
    for (int i = t; i < 960; i += 256) th_s[i] = th[i];
    int n0 = blockIdx.x * 8;
    const float4* in4 = (const float4*)(in + (size_t)n0 * 1024);
#pragma unroll
    for (int i = 0; i < 8; ++i) {
        ((float4*)&rows[i][0])[t] = in4[i * 256 + t];
    }
    __syncthreads();
#pragma unroll
    for (int i = 0; i < 2; ++i) {
        int id = i * 256 + t;
        int c = id >> 3;
        int r = id & 7;
        int node = 0;
        const float* trow = &rows[r][0];
#pragma unroll
        for (int lvl = 0; lvl < 4; ++lvl) {
            float x   = trow[dims_s[c * 4 + lvl]];
            float thv = th_s[c * 15 + node];
            node = 2 * node + 1 + ((x > thv) ? 1 : 0);
        }
        leaf[(size_t)c * N_ROWS + n0 + r] = (uint8_t)(node - 15);
    }
}

__global__ __launch_bounds__(512) void k_accum(const float* __restrict__ lutT,
                                               const uint8_t* __restrict__ leaf,
                                               float* __restrict__ out) {
    __shared__ float4 sl[2][16][32];
    int t     = threadIdx.x;
    int mlane = t & 31;
    int ngrp  = t >> 5;
    int wave  = t >> 6;
    int lane  = t & 63;
    int srow  = 2 * wave + (lane >> 5);
    int schunk = lane & 31;
    int m0 = blockIdx.x * 128;
    int n0 = blockIdx.y * 128;
    const float4* lutT4 = (const float4*)lutT;
    auto stage = [&](int buf, int c) {
        const float4* src = lutT4 + ((size_t)(c * 16 + srow) * 256) + (m0 >> 2) + schunk;
        __builtin_amdgcn_global_load_lds((const __attribute__((address_space(1))) void*)src,
                                         (__attribute__((address_space(3))) void*)&sl[buf][2 * wave][0],
                                         16, 0, 0);
    };
    float4 acc[8];
#pragma unroll
    for (int j = 0; j < 8; ++j) acc[j] = make_float4(0.f, 0.f, 0.f, 0.f);
    const uint8_t* lp = leaf + n0 + ngrp * 8;
    uint64_t lv = *(const uint64_t*)lp;
    stage(0, 0);
#pragma unroll 2
    for (int c = 0; c < 64; ++c) {
        __syncthreads();
        if (c < 63) stage((c + 1) & 1, c + 1);
        uint64_t lv_next = (c < 63) ? *(const uint64_t*)(lp + (size_t)(c + 1) * N_ROWS) : 0ull;
        int buf = c & 1;
#pragma unroll
        for (int j = 0; j < 8; ++j) {
            int k = (int)((lv >> (8 * j)) & 15);
            float4 v = sl[buf][k][mlane];
            acc[j].x += v.x; acc[j].y += v.y; acc[j].z += v.z; acc[j].w += v.w;
        }
        lv = lv_next;
    }
    float4* out4 = (float4*)out;
#pragma unroll
    for (int j = 0; j < 8; ++j) {
        int n = n0 + ngrp * 8 + j;
        out4[(size_t)n * 256 + (m0 >> 2) + mlane] = acc[j];
    }
}

extern "C" void kernel_launch(void* const* d_in, const int* in_sizes, int n_in,
                              void* d_out, int out_size, void* d_ws, size_t ws_size,
                              hipStream_t stream) {
    const float* inputMatrix = (const float*)d_in[0];
    const int*   dims        = (const int*)d_in[1];
    const float* thresholds  = (const float*)d_in[2];
    const float* lut         = (const float*)d_in[3];
    float* out = (float*)d_out;

    float* lutT = (float*)d_ws;                                    // 4 MB

    const size_t NEED = (size_t)4 * 1024 * 1024   // lutT
                      + (size_t)16 * 1024 * 1024  // Pt (f16, tiled)
                      + (size_t)2 * 1024 * 1024;  // code16

    if (ws_size >= NEED) {
        _Float16* Pt     = (_Float16*)((char*)d_ws + (size_t)4 * 1024 * 1024); // 16 MB
        uint16_t* code16 = (uint16_t*)((char*)d_ws + (size_t)20 * 1024 * 1024); // 2 MB

        k_transpose<<<dim3(32, 32), dim3(32, 8), 0, stream>>>(lut, lutT);
        k_build_ht<<<dim3(256, 32), 256, 0, stream>>>(lutT, Pt);
        k_encode3<<<N_ROWS / 8, 256, 0, stream>>>(inputMatrix, dims, thresholds, code16);
        k_accum7<<<dim3(M_OUT / 32, N_ROWS / 512), 512, 0, stream>>>(Pt, code16, out);
    } else {
        uint8_t* leaf = (uint8_t*)d_ws + (size_t)4 * 1024 * 1024;
        k_transpose<<<dim3(32, 32), dim3(32, 8), 0, stream>>>(lut, lutT);
        k_encode<<<N_ROWS / 8, 256, 0, stream>>>(inputMatrix, dims, thresholds, leaf);
        k_accum<<<dim3(M_OUT / 128, N_ROWS / 128), 512, 0, stream>>>(lutT, leaf, out);
    }
}